// Round 9
// baseline (76.228 us; speedup 1.0000x reference)
//
#include <hip/hip_runtime.h>
#include <math.h>

#define N_QUBITS 11
#define DIM 2048

// ---------------------------------------------------------------------------
// TRANSFER-MATRIX, FULLY TABULATED (R8 algebra, re-associated).
//
//   out[j] = Re( r(b0) · M1(b1)·...·M9(b9) · t10(b10) ),   b = j ^ (j<<1)
//   M_q(b) = [[d0,d1],[e0,e1]],  d0=V[b,0]c(0), d1=V[b,1]c(1),
//                                e0=V[b,0]c(1), e1=V[b,1]c(0)
//   (K-table semantics HW-validated in R8, absmax 4.9e-4)
//
// By associativity, split at the lane boundary:
//   H[b0..b4]   = r(b0)·M1·M2·M3·M4          (32 row-vectors, LDS)
//   Tail[b5..b10] = M5·M6·M7·M8·M9·t10       (64 col-vectors, LDS)
//   out = Re( H · Tail )                      (4 FMA per output)
// Tail built from pair tables A=M5·M6 [4], B=M7·M8 [4], c=M9·t10 [4].
//
// Main loop per lane: 1 Tail b128 read + 16 H b128 reads (2-way broadcast /
// stride-1 = conflict-free) + 64 FMA + 4 dwordx4 stores. R8 did 44 b128
// reads + ~460 VALU per lane; this is the DS/VALU floor for this split.
//
// j = 1024w + 16L + n (two waves/block, one block per batch element):
//   b0=n0, b1=n1^n0, b2=n2^n1, b3=n3^n2      -> bits of (n^(n<<1))&15
//   b4=L0^n3
//   b5..b9 = bits 0..4 of z = L^(L>>1),  b10 = w^L5
// Peak ~30 live floats -- far under the 64-VGPR clamp (R2/R4/R6 lesson).
// ---------------------------------------------------------------------------

__global__ __launch_bounds__(128)
void pqc_sim_kernel(const float* __restrict__ theta,
                    const int* __restrict__ positions,
                    float* __restrict__ out)
{
    __shared__ __align__(16) float K[N_QUBITS][2][8];  // transfer coeffs
    __shared__ __align__(16) float H[32][4];           // head row-vectors
    __shared__ __align__(16) float Am[4][8];           // M5*M6
    __shared__ __align__(16) float Bm[4][8];           // M7*M8
    __shared__ __align__(16) float Cv[4][4];           // M9 * t10
    __shared__ __align__(16) float Tail[64][4];        // tail col-vectors

    const int t   = threadIdx.x;
    const int b   = blockIdx.x;
    const int pos = positions[b];

    // ---- Phase 1: K rows straight from theta (44 threads, both gates) ----
    if (t < 44) {
        const int q = t >> 1, bsel = t & 1;
        const float* th1 = theta + ((size_t)pos * 2 + 0) * (3 * N_QUBITS) + 3 * q;
        const float* th2 = theta + ((size_t)pos * 2 + 1) * (3 * N_QUBITS) + 3 * q;

        // layer-1 gate, column 0 only: c(0)=U[0][0], c(1)=U[1][0]
        float c0r, c0i, c1r, c1i;
        {
            float sa, ca, sb, cb, sg, cg;
            sincosf(th1[0] * 0.5f, &sa, &ca);
            sincosf(th1[1] * 0.5f, &sb, &cb);
            sincosf(th1[2] * 0.5f, &sg, &cg);
            const float m00r =  cb * ca, m00i =  sb * sa;
            const float m10r =  sb * ca, m10i = -cb * sa;
            c0r = m00r * cg + m00i * sg;  c0i = m00i * cg - m00r * sg;
            c1r = m10r * cg - m10i * sg;  c1i = m10i * cg + m10r * sg;
        }
        // layer-2 gate, row bsel: V[b,0], V[b,1]
        float v0r, v0i, v1r, v1i;
        {
            float sa, ca, sb, cb, sg, cg;
            sincosf(th2[0] * 0.5f, &sa, &ca);
            sincosf(th2[1] * 0.5f, &sb, &cb);
            sincosf(th2[2] * 0.5f, &sg, &cg);
            const float m00r =  cb * ca, m00i =  sb * sa;
            const float m01r = -sb * ca, m01i = -cb * sa;
            const float m10r =  sb * ca, m10i = -cb * sa;
            const float m11r =  cb * ca, m11i = -sb * sa;
            if (bsel == 0) {   // row 0 *= e^{-ig}
                v0r = m00r * cg + m00i * sg;  v0i = m00i * cg - m00r * sg;
                v1r = m01r * cg + m01i * sg;  v1i = m01i * cg - m01r * sg;
            } else {           // row 1 *= e^{+ig}
                v0r = m10r * cg - m10i * sg;  v0i = m10i * cg + m10r * sg;
                v1r = m11r * cg - m11i * sg;  v1i = m11i * cg + m11r * sg;
            }
        }
        K[q][bsel][0] = v0r * c0r - v0i * c0i;   // d0 = V[b,0]*c(0)
        K[q][bsel][1] = v0r * c0i + v0i * c0r;
        K[q][bsel][2] = v1r * c1r - v1i * c1i;   // d1 = V[b,1]*c(1)
        K[q][bsel][3] = v1r * c1i + v1i * c1r;
        K[q][bsel][4] = v0r * c1r - v0i * c1i;   // e0 = V[b,0]*c(1)
        K[q][bsel][5] = v0r * c1i + v0i * c1r;
        K[q][bsel][6] = v1r * c0r - v1i * c0i;   // e1 = V[b,1]*c(0)
        K[q][bsel][7] = v1r * c0i + v1i * c0r;
    }
    __syncthreads();

    // ---- Phase 2: H rows (t<32), pair tables A/B/c (t=32..43) ----
    if (t < 32) {
        // row = r(h0) = (K[0][h0].d0, K[0][h0].d1), then x M1(h1)..M4(h4)
        float ar = K[0][t & 1][0], ai = K[0][t & 1][1];
        float br = K[0][t & 1][2], bi = K[0][t & 1][3];
        #pragma unroll
        for (int q = 1; q < 5; ++q) {
            const float* Kq = &K[q][(t >> q) & 1][0];
            const float d0r = Kq[0], d0i = Kq[1], d1r = Kq[2], d1i = Kq[3];
            const float e0r = Kq[4], e0i = Kq[5], e1r = Kq[6], e1i = Kq[7];
            const float nar = ar * d0r - ai * d0i + br * e0r - bi * e0i;
            const float nai = ar * d0i + ai * d0r + br * e0i + bi * e0r;
            const float nbr = ar * d1r - ai * d1i + br * e1r - bi * e1i;
            const float nbi = ar * d1i + ai * d1r + br * e1i + bi * e1r;
            ar = nar; ai = nai; br = nbr; bi = nbi;
        }
        H[t][0] = ar; H[t][1] = ai; H[t][2] = br; H[t][3] = bi;
    } else if (t < 40) {
        // matrix pair products: A[i] = M5(i0)*M6(i1), B[i] = M7(i0)*M8(i1)
        const int i = (t - 32) & 3;
        const int qlo = (t < 36) ? 5 : 7;
        float* dst = (t < 36) ? &Am[i][0] : &Bm[i][0];
        const float* Ka = &K[qlo][i & 1][0];        // left matrix
        const float* Kb = &K[qlo + 1][(i >> 1) & 1][0]; // right matrix
        // P[r][c] = sum_k L[r][k] * R[k][c];  L,R = [[d0,d1],[e0,e1]]
        #pragma unroll
        for (int r = 0; r < 2; ++r) {
            const float l0r = Ka[r * 4 + 0], l0i = Ka[r * 4 + 1];
            const float l1r = Ka[r * 4 + 2], l1i = Ka[r * 4 + 3];
            #pragma unroll
            for (int c = 0; c < 2; ++c) {
                const float r0r = Kb[c * 2 + 0],     r0i = Kb[c * 2 + 1];
                const float r1r = Kb[4 + c * 2 + 0], r1i = Kb[4 + c * 2 + 1];
                dst[r * 4 + c * 2 + 0] = l0r * r0r - l0i * r0i + l1r * r1r - l1i * r1i;
                dst[r * 4 + c * 2 + 1] = l0r * r0i + l0i * r0r + l1r * r1i + l1i * r1r;
            }
        }
    } else if (t < 44) {
        // c[z4 + 2*b10] = M9(z4) * t10(b10);  t10 = (d0+d1, e0+e1) of K[10]
        const int i = t - 40, z4 = i & 1, b10 = (i >> 1) & 1;
        const float* Kt = &K[10][b10][0];
        const float t0r = Kt[0] + Kt[2], t0i = Kt[1] + Kt[3];
        const float t1r = Kt[4] + Kt[6], t1i = Kt[5] + Kt[7];
        const float* K9 = &K[9][z4][0];
        Cv[i][0] = K9[0] * t0r - K9[1] * t0i + K9[2] * t1r - K9[3] * t1i;
        Cv[i][1] = K9[0] * t0i + K9[1] * t0r + K9[2] * t1i + K9[3] * t1r;
        Cv[i][2] = K9[4] * t0r - K9[5] * t0i + K9[6] * t1r - K9[7] * t1i;
        Cv[i][3] = K9[4] * t0i + K9[5] * t0r + K9[6] * t1i + K9[7] * t1r;
    }
    __syncthreads();

    // ---- Phase 3: Tail[e] = A[e&3] * (B[(e>>2)&3] * c[(e>>4)&3]) ----
    if (t < 64) {
        const float* cb_ = &Cv[(t >> 4) & 3][0];
        const float* Bq  = &Bm[(t >> 2) & 3][0];
        const float v0r = Bq[0] * cb_[0] - Bq[1] * cb_[1] + Bq[2] * cb_[2] - Bq[3] * cb_[3];
        const float v0i = Bq[0] * cb_[1] + Bq[1] * cb_[0] + Bq[2] * cb_[3] + Bq[3] * cb_[2];
        const float v1r = Bq[4] * cb_[0] - Bq[5] * cb_[1] + Bq[6] * cb_[2] - Bq[7] * cb_[3];
        const float v1i = Bq[4] * cb_[1] + Bq[5] * cb_[0] + Bq[6] * cb_[3] + Bq[7] * cb_[2];
        const float* Aq = &Am[t & 3][0];
        Tail[t][0] = Aq[0] * v0r - Aq[1] * v0i + Aq[2] * v1r - Aq[3] * v1i;
        Tail[t][1] = Aq[0] * v0i + Aq[1] * v0r + Aq[2] * v1i + Aq[3] * v1r;
        Tail[t][2] = Aq[4] * v0r - Aq[5] * v0i + Aq[6] * v1r - Aq[7] * v1i;
        Tail[t][3] = Aq[4] * v0i + Aq[5] * v0r + Aq[6] * v1i + Aq[7] * v1r;
    }
    __syncthreads();

    // ---- Main: 1 Tail read + 16 H reads + 64 FMA + 4 stores per lane ----
    const int w = t >> 6, L = t & 63;
    const int z    = (L ^ (L >> 1)) & 31;
    const int tidx = z | (((w ^ (L >> 5)) & 1) << 5);
    const float4 T = *(const float4*)&Tail[tidx][0];   // (T0r,T0i,T1r,T1i)
    const int L0h = (L & 1) << 4;

    float* orow = out + (size_t)b * DIM + w * 1024 + L * 16;
    #pragma unroll
    for (int g = 0; g < 4; ++g) {
        float4 o;
        #pragma unroll
        for (int e = 0; e < 4; ++e) {
            const int n = 4 * g + e;
            const int hidx = (((n ^ (n << 1)) & 15) | ((n >> 3) << 4)) ^ L0h;
            const float4 h = *(const float4*)&H[hidx][0];
            const float v = h.x * T.x - h.y * T.y + h.z * T.z - h.w * T.w;
            if (e == 0) o.x = v; else if (e == 1) o.y = v;
            else if (e == 2) o.z = v; else o.w = v;
        }
        *(float4*)(orow + 4 * g) = o;
    }
}

extern "C" void kernel_launch(void* const* d_in, const int* in_sizes, int n_in,
                              void* d_out, int out_size, void* d_ws, size_t ws_size,
                              hipStream_t stream)
{
    const float* theta     = (const float*)d_in[0];
    const int*   positions = (const int*)d_in[1];
    float*       out       = (float*)d_out;
    const int B = in_sizes[1];   // 4096

    pqc_sim_kernel<<<B, 128, 0, stream>>>(theta, positions, out);
}